// Round 1
// baseline (195.069 us; speedup 1.0000x reference)
//
#include <hip/hip_runtime.h>

#define K_TOP   205
#define ROW     4096
#define NTHR    256
#define EPT     16          // elements per thread = ROW / NTHR
#define PADIDX(i) ((i) + ((i) >> 4))   // +1 pad per 16 elements (stride 17, coprime 32)

// monotone key transform: order(key) == order(float), ascending
__device__ __forceinline__ unsigned key_of(float f) {
    unsigned b = __float_as_uint(f);
    unsigned m = ((unsigned)((int)b >> 31)) | 0x80000000u;
    return b ^ m;
}
__device__ __forceinline__ float val_of(unsigned u) {
    unsigned m = (u & 0x80000000u) ? 0x80000000u : 0xFFFFFFFFu;
    return __uint_as_float(u ^ m);
}

__global__ __launch_bounds__(NTHR)
void kwta_kernel(const float* __restrict__ x, float* __restrict__ out) {
    __shared__ unsigned keys[ROW + (ROW >> 4)];   // 4352 u32, padded
    __shared__ unsigned hist[4][257];             // per-wave copies, +1 pad breaks copy aliasing
    __shared__ unsigned wred[4];
    __shared__ unsigned s_bin, s_kk;

    const int tid  = threadIdx.x;
    const int lane = tid & 63;
    const int wave = tid >> 6;
    const long long row = blockIdx.x;

    const float4* __restrict__ xin = (const float4*)(x + row * (long long)ROW);

    // ---- load row, transform to sortable keys, store padded into LDS ----
#pragma unroll
    for (int j = 0; j < 4; ++j) {
        float4 v = xin[tid + NTHR * j];
        int i = 4 * (tid + NTHR * j);
        int p = PADIDX(i);              // i % 16 in {0,4,8,12} -> p..p+3 contiguous
        keys[p + 0] = key_of(v.x);
        keys[p + 1] = key_of(v.y);
        keys[p + 2] = key_of(v.z);
        keys[p + 3] = key_of(v.w);
    }
    __syncthreads();

    // ---- 4-pass radix select (MSB->LSB) for the K-th largest key ----
    unsigned prefix = 0, pmask = 0;
    unsigned kk = K_TOP;

    for (int shift = 24; shift >= 0; shift -= 8) {
        hist[wave][lane]       = 0;
        hist[wave][lane + 64]  = 0;
        hist[wave][lane + 128] = 0;
        hist[wave][lane + 192] = 0;
        __syncthreads();

#pragma unroll
        for (int j = 0; j < EPT; ++j) {
            int i = tid + NTHR * j;          // strided: conflict-free-ish reads
            unsigned u = keys[PADIDX(i)];
            if ((u & pmask) == prefix)
                atomicAdd(&hist[wave][(u >> shift) & 255u], 1u);
        }
        __syncthreads();

        // thread b = tid owns bin b: reduce the 4 wave copies
        unsigned cnt = hist[0][tid] + hist[1][tid] + hist[2][tid] + hist[3][tid];

        // inclusive suffix-sum within wave (bins 64*wave .. 64*wave+63)
        unsigned v = cnt;
#pragma unroll
        for (int off = 1; off < 64; off <<= 1) {
            unsigned n = __shfl_down(v, off, 64);
            if (lane + off < 64) v += n;
        }
        if (lane == 0) wred[wave] = v;       // wave total
        __syncthreads();

        unsigned carry = 0;
        for (int w = wave + 1; w < 4; ++w) carry += wred[w];
        unsigned S   = v + carry;            // count of keys in bins >= mine
        unsigned Sex = S - cnt;              // count of keys in bins >  mine

        if (S >= kk && Sex < kk) {           // unique winner (needs cnt>0)
            s_bin = (unsigned)tid;
            s_kk  = kk - Sex;
        }
        __syncthreads();

        prefix |= s_bin << shift;
        pmask  |= 0xFFu << shift;
        kk = s_kk;
        __syncthreads();
    }

    const unsigned T = prefix;   // exact key of the K-th largest element
    const unsigned r = kk;       // how many ties (== T) to keep, lowest index first

    // ---- index-ordered tie ranking: exclusive prefix of eq-counts ----
    const int base = tid * EPT;  // contiguous chunk; padded stride 17 -> conflict-free
    unsigned cntEq = 0;
#pragma unroll
    for (int j = 0; j < EPT; ++j)
        cntEq += (keys[PADIDX(base + j)] == T) ? 1u : 0u;

    unsigned inc = cntEq;
#pragma unroll
    for (int off = 1; off < 64; off <<= 1) {
        unsigned n = __shfl_up(inc, off, 64);
        if (lane >= off) inc += n;
    }
    if (lane == 63) wred[wave] = inc;
    __syncthreads();

    unsigned P = inc - cntEq;
    for (int w = 0; w < wave; ++w) P += wred[w];

    // ---- decide keep/zero, write output floats in-place over keys ----
    unsigned running = P;
#pragma unroll
    for (int j = 0; j < EPT; ++j) {
        int p = PADIDX(base + j);
        unsigned u = keys[p];
        bool keep;
        if (u == T) { keep = (running < r); ++running; }
        else        { keep = (u > T); }
        keys[p] = keep ? __float_as_uint(val_of(u)) : 0u;
    }
    __syncthreads();

    // ---- coalesced float4 store ----
    float4* __restrict__ o = (float4*)(out + row * (long long)ROW);
#pragma unroll
    for (int j = 0; j < 4; ++j) {
        int i = 4 * (tid + NTHR * j);
        int p = PADIDX(i);
        float4 v;
        v.x = __uint_as_float(keys[p + 0]);
        v.y = __uint_as_float(keys[p + 1]);
        v.z = __uint_as_float(keys[p + 2]);
        v.w = __uint_as_float(keys[p + 3]);
        o[tid + NTHR * j] = v;
    }
}

extern "C" void kernel_launch(void* const* d_in, const int* in_sizes, int n_in,
                              void* d_out, int out_size, void* d_ws, size_t ws_size,
                              hipStream_t stream) {
    const float* x = (const float*)d_in[0];
    float* out = (float*)d_out;
    const int rows = out_size / ROW;   // 16384
    kwta_kernel<<<rows, NTHR, 0, stream>>>(x, out);
}

// Round 2
// 112.037 us; speedup vs baseline: 1.7411x; 1.7411x over previous
//
#include <hip/hip_runtime.h>

#define K_TOP 205
#define ROW   4096
#define NTHR  256
#define RPB   4              // rows per block (one row per wave)
#define CAP   384            // candidate buffer per wave
#define NSLOT (CAP / 64)     // candidate regs per lane

// monotone key transform: ascending key order == ascending float order
__device__ __forceinline__ unsigned key_of_bits(unsigned b) {
    return b ^ (((unsigned)((int)b >> 31)) | 0x80000000u);
}
__device__ __forceinline__ float val_of(unsigned u) {
    return __uint_as_float(u ^ ((u & 0x80000000u) ? 0x80000000u : 0xFFFFFFFFu));
}

__device__ __forceinline__ unsigned wave_sum(unsigned v) {
#pragma unroll
    for (int off = 1; off < 64; off <<= 1) v += __shfl_xor(v, off, 64);
    return v;
}

__global__ __launch_bounds__(NTHR)
void kwta_kernel(const float* __restrict__ x, float* __restrict__ out) {
    __shared__ unsigned cand[RPB][CAP];

    const int lane = (int)(threadIdx.x & 63u);
    const int wave = (int)(threadIdx.x >> 6u);
    const long long row = (long long)blockIdx.x * RPB + wave;

    const uint4* __restrict__ xin = (const uint4*)(x + row * (long long)ROW);

    // pivot keys (compile-time constants): bracket the ~95th percentile of N(0,1)
    const unsigned KLO = key_of_bits(__float_as_uint(1.45f));   // 0xBFB9999A
    const unsigned KHI = key_of_bits(__float_as_uint(1.85f));   // 0xBFECCCCD

    // ---- load row into registers, transform to keys, count vs both pivots ----
    uint4 k[16];
    unsigned clo_l = 0, chi_l = 0;
#pragma unroll
    for (int j = 0; j < 16; ++j) {
        uint4 v = xin[j * 64 + lane];
        v.x = key_of_bits(v.x); v.y = key_of_bits(v.y);
        v.z = key_of_bits(v.z); v.w = key_of_bits(v.w);
        k[j] = v;
        clo_l += (unsigned)(v.x >= KLO) + (unsigned)(v.y >= KLO)
               + (unsigned)(v.z >= KLO) + (unsigned)(v.w >= KLO);
        chi_l += (unsigned)(v.x >= KHI) + (unsigned)(v.y >= KHI)
               + (unsigned)(v.z >= KHI) + (unsigned)(v.w >= KHI);
    }
    const unsigned c_lo = wave_sum(clo_l);      // #(key >= KLO), wave-global
    const unsigned c_hi = wave_sum(chi_l);      // #(key >= KHI)
    const unsigned M    = c_lo - c_hi;          // candidates in [KLO, KHI)

    unsigned T, S, Sex;                          // threshold key, #>=T, #>T

    const bool fast = (c_lo >= K_TOP) && (c_hi < K_TOP) && (M <= CAP);
    if (fast) {
        // ---- compact window candidates into per-wave LDS (no atomics) ----
#pragma unroll
        for (int s = 0; s < NSLOT; ++s) cand[wave][lane + 64 * s] = 0u;

        unsigned wl = clo_l - chi_l;            // this lane's window count
        unsigned inc = wl;
#pragma unroll
        for (int off = 1; off < 64; off <<= 1) {
            unsigned n = __shfl_up(inc, off, 64);
            if (lane >= off) inc += n;
        }
        unsigned pos = inc - wl;                // exclusive prefix = my base slot
#pragma unroll
        for (int j = 0; j < 16; ++j) {
            if (k[j].x >= KLO && k[j].x < KHI) cand[wave][pos++] = k[j].x;
            if (k[j].y >= KLO && k[j].y < KHI) cand[wave][pos++] = k[j].y;
            if (k[j].z >= KLO && k[j].z < KHI) cand[wave][pos++] = k[j].z;
            if (k[j].w >= KLO && k[j].w < KHI) cand[wave][pos++] = k[j].w;
        }

        unsigned cs[NSLOT];
#pragma unroll
        for (int s = 0; s < NSLOT; ++s) cs[s] = cand[wave][lane + 64 * s];

        // ---- bisection on key interval [KLO, KHI), counting candidates only ----
        unsigned lo = KLO, hi = KHI, cl = c_lo, ch = c_hi;
        while (hi - lo > 1u) {
            unsigned mid = lo + ((hi - lo) >> 1);
            unsigned c = 0;
#pragma unroll
            for (int s = 0; s < NSLOT; ++s) c += (unsigned)(cs[s] >= mid);
            c = wave_sum(c) + c_hi;             // cnt(>= mid) over full row
            if (c >= K_TOP) { lo = mid; cl = c; } else { hi = mid; ch = c; }
        }
        T = lo; S = cl; Sex = ch;
    } else {
        // ---- rare exact fallback: bisect full key space, count from registers ----
        unsigned lo = 0u, hi = 0xFFFFFFFFu;
        unsigned cl = ROW;                      // cnt(>=0) == 4096
        unsigned chl = 0;
#pragma unroll
        for (int j = 0; j < 16; ++j) {
            chl += (unsigned)(k[j].x >= hi) + (unsigned)(k[j].y >= hi)
                 + (unsigned)(k[j].z >= hi) + (unsigned)(k[j].w >= hi);
        }
        unsigned ch = wave_sum(chl);
        if (ch >= K_TOP) {                      // pathological: >=K copies of max key
            lo = hi; cl = ch; ch = 0;
        } else {
            while (hi - lo > 1u) {
                unsigned mid = lo + ((hi - lo) >> 1);
                unsigned cc = 0;
#pragma unroll
                for (int j = 0; j < 16; ++j) {
                    cc += (unsigned)(k[j].x >= mid) + (unsigned)(k[j].y >= mid)
                        + (unsigned)(k[j].z >= mid) + (unsigned)(k[j].w >= mid);
                }
                cc = wave_sum(cc);
                if (cc >= K_TOP) { lo = mid; cl = cc; } else { hi = mid; ch = cc; }
            }
        }
        T = lo; S = cl; Sex = ch;
    }

    const unsigned r  = K_TOP - Sex;            // ties (== T) to keep, lowest index first
    const unsigned eq = S - Sex;                // total ties

    float4* __restrict__ o = (float4*)(out + row * (long long)ROW);

    if (eq == r) {
        // common case: keep everything >= T
#pragma unroll
        for (int j = 0; j < 16; ++j) {
            float4 v;
            v.x = (k[j].x >= T) ? val_of(k[j].x) : 0.0f;
            v.y = (k[j].y >= T) ? val_of(k[j].y) : 0.0f;
            v.z = (k[j].z >= T) ? val_of(k[j].z) : 0.0f;
            v.w = (k[j].w >= T) ? val_of(k[j].w) : 0.0f;
            o[j * 64 + lane] = v;
        }
    } else {
        // rare: rank ties by flat index (j, lane, c) and keep the first r
        unsigned rank_base = 0;
#pragma unroll
        for (int j = 0; j < 16; ++j) {
            unsigned e = (unsigned)(k[j].x == T) + (unsigned)(k[j].y == T)
                       + (unsigned)(k[j].z == T) + (unsigned)(k[j].w == T);
            unsigned inc = e;
#pragma unroll
            for (int off = 1; off < 64; off <<= 1) {
                unsigned n = __shfl_up(inc, off, 64);
                if (lane >= off) inc += n;
            }
            unsigned rk  = rank_base + (inc - e);        // exclusive prefix
            unsigned tot = __shfl(inc, 63, 64);          // chunk total

            float4 v;
            if (k[j].x == T) { v.x = (rk < r) ? val_of(k[j].x) : 0.0f; ++rk; }
            else             { v.x = (k[j].x > T) ? val_of(k[j].x) : 0.0f; }
            if (k[j].y == T) { v.y = (rk < r) ? val_of(k[j].y) : 0.0f; ++rk; }
            else             { v.y = (k[j].y > T) ? val_of(k[j].y) : 0.0f; }
            if (k[j].z == T) { v.z = (rk < r) ? val_of(k[j].z) : 0.0f; ++rk; }
            else             { v.z = (k[j].z > T) ? val_of(k[j].z) : 0.0f; }
            if (k[j].w == T) { v.w = (rk < r) ? val_of(k[j].w) : 0.0f; ++rk; }
            else             { v.w = (k[j].w > T) ? val_of(k[j].w) : 0.0f; }
            o[j * 64 + lane] = v;

            rank_base += tot;
        }
    }
}

extern "C" void kernel_launch(void* const* d_in, const int* in_sizes, int n_in,
                              void* d_out, int out_size, void* d_ws, size_t ws_size,
                              hipStream_t stream) {
    const float* x = (const float*)d_in[0];
    float* out = (float*)d_out;
    const int rows = out_size / ROW;            // 16384
    kwta_kernel<<<rows / RPB, NTHR, 0, stream>>>(x, out);
}

// Round 4
// 110.203 us; speedup vs baseline: 1.7701x; 1.0166x over previous
//
#include <hip/hip_runtime.h>

#define K_TOP 205
#define ROW   4096
#define NTHR  256
#define RPB   4              // rows per block (one row per wave)
#define CAP   384            // candidate buffer per wave (mean M=169, +17 sigma)
#define NSLOT (CAP / 64)     // candidate regs per lane

#define FLO 1.45f            // bracket the 95th percentile of N(0,1): z=1.645 +/- ~6 sigma
#define FHI 1.85f

typedef float fx4 __attribute__((ext_vector_type(4)));   // native vector: nontemporal-ok

// monotone key transform (ascending key == ascending float), used for bisection grid
__device__ __forceinline__ unsigned key_of_bits(unsigned b) {
    return b ^ (((unsigned)((int)b >> 31)) | 0x80000000u);
}
__device__ __forceinline__ float val_of(unsigned u) {
    return __uint_as_float(u ^ ((u & 0x80000000u) ? 0x80000000u : 0xFFFFFFFFu));
}
__device__ __forceinline__ unsigned wave_sum(unsigned v) {
#pragma unroll
    for (int off = 1; off < 64; off <<= 1) v += __shfl_xor(v, off, 64);
    return v;
}

__global__ __launch_bounds__(NTHR, 4)
void kwta_kernel(const float* __restrict__ x, float* __restrict__ out) {
    __shared__ float cand[RPB][CAP];

    const int lane = (int)(threadIdx.x & 63u);
    const int wave = (int)(threadIdx.x >> 6u);
    const long long row = (long long)blockIdx.x * RPB + wave;

    const fx4* __restrict__ xin = (const fx4*)(x + row * (long long)ROW);

    // ---- load row into registers (streaming), count vs both pivots ----
    fx4 f[16];
    unsigned clo_l = 0, chi_l = 0;
#pragma unroll
    for (int j = 0; j < 16; ++j) {
        fx4 v = __builtin_nontemporal_load(&xin[j * 64 + lane]);
        f[j] = v;
        clo_l += (unsigned)(v.x >= FLO) + (unsigned)(v.y >= FLO)
               + (unsigned)(v.z >= FLO) + (unsigned)(v.w >= FLO);
        chi_l += (unsigned)(v.x >= FHI) + (unsigned)(v.y >= FHI)
               + (unsigned)(v.z >= FHI) + (unsigned)(v.w >= FHI);
    }
    const unsigned c_lo = wave_sum(clo_l);      // #(x >= FLO), wave-global
    const unsigned c_hi = wave_sum(chi_l);      // #(x >= FHI)
    const unsigned M    = c_lo - c_hi;          // candidates in [FLO, FHI)

    float Tf; unsigned S, Sex;                  // threshold value, #>=T, #>T

    const bool fast = (c_lo >= K_TOP) && (c_hi < K_TOP) && (M <= CAP);
    if (fast) {
        // ---- compact window candidates into per-wave LDS (no atomics, no barrier) ----
#pragma unroll
        for (int s = 0; s < NSLOT; ++s) cand[wave][lane + 64 * s] = 0.0f;

        unsigned wl = clo_l - chi_l;            // this lane's window count
        unsigned inc = wl;
#pragma unroll
        for (int off = 1; off < 64; off <<= 1) {
            unsigned n = __shfl_up(inc, off, 64);
            if (lane >= off) inc += n;
        }
        unsigned pos = inc - wl;                // exclusive prefix = my base slot
#pragma unroll
        for (int j = 0; j < 16; ++j) {
            if (f[j].x >= FLO && f[j].x < FHI) cand[wave][pos++] = f[j].x;
            if (f[j].y >= FLO && f[j].y < FHI) cand[wave][pos++] = f[j].y;
            if (f[j].z >= FLO && f[j].z < FHI) cand[wave][pos++] = f[j].z;
            if (f[j].w >= FLO && f[j].w < FHI) cand[wave][pos++] = f[j].w;
        }

        float cs[NSLOT];
#pragma unroll
        for (int s = 0; s < NSLOT; ++s) cs[s] = cand[wave][lane + 64 * s];

        // ---- bisection on key grid, counting via ballot+popcount (no DS ops) ----
        const unsigned KLO = key_of_bits(__float_as_uint(FLO));
        const unsigned KHI = key_of_bits(__float_as_uint(FHI));
        unsigned lo = KLO, hi = KHI, cl = c_lo, ch = c_hi;
        while (hi - lo > 1u) {
            unsigned mid  = lo + ((hi - lo) >> 1);
            float     mf  = val_of(mid);        // uniform scalar
            unsigned c = c_hi;
#pragma unroll
            for (int s = 0; s < NSLOT; ++s)
                c += (unsigned)__popcll(__ballot(cs[s] >= mf));
            if (c >= K_TOP) { lo = mid; cl = c; } else { hi = mid; ch = c; }
        }
        Tf = val_of(lo); S = cl; Sex = ch;
    } else {
        // ---- rare exact fallback: integer-key bisection over full key space ----
        unsigned lo = 0u, hi = 0xFFFFFFFFu, cl = ROW, ch;
        {
            unsigned chl = 0;
#pragma unroll
            for (int j = 0; j < 16; ++j) {
                chl += (unsigned)(key_of_bits(__float_as_uint(f[j].x)) >= hi)
                     + (unsigned)(key_of_bits(__float_as_uint(f[j].y)) >= hi)
                     + (unsigned)(key_of_bits(__float_as_uint(f[j].z)) >= hi)
                     + (unsigned)(key_of_bits(__float_as_uint(f[j].w)) >= hi);
            }
            ch = wave_sum(chl);
        }
        if (ch >= K_TOP) { lo = hi; cl = ch; ch = 0; }
        else {
            while (hi - lo > 1u) {
                unsigned mid = lo + ((hi - lo) >> 1);
                unsigned cc = 0;
#pragma unroll
                for (int j = 0; j < 16; ++j) {
                    cc += (unsigned)(key_of_bits(__float_as_uint(f[j].x)) >= mid)
                        + (unsigned)(key_of_bits(__float_as_uint(f[j].y)) >= mid)
                        + (unsigned)(key_of_bits(__float_as_uint(f[j].z)) >= mid)
                        + (unsigned)(key_of_bits(__float_as_uint(f[j].w)) >= mid);
                }
                cc = wave_sum(cc);
                if (cc >= K_TOP) { lo = mid; cl = cc; } else { hi = mid; ch = cc; }
            }
        }
        Tf = val_of(lo); S = cl; Sex = ch;
    }

    const unsigned r  = K_TOP - Sex;            // ties (== Tf) to keep, lowest index first
    const unsigned eq = S - Sex;                // total ties

    fx4* __restrict__ o = (fx4*)(out + row * (long long)ROW);

    if (eq == r) {
        // common case: keep everything >= Tf
#pragma unroll
        for (int j = 0; j < 16; ++j) {
            fx4 v = f[j], w;
            w.x = (v.x >= Tf) ? v.x : 0.0f;
            w.y = (v.y >= Tf) ? v.y : 0.0f;
            w.z = (v.z >= Tf) ? v.z : 0.0f;
            w.w = (v.w >= Tf) ? v.w : 0.0f;
            __builtin_nontemporal_store(w, &o[j * 64 + lane]);
        }
    } else {
        // rare: rank ties by flat index (j, lane, c) and keep the first r
        unsigned rank_base = 0;
#pragma unroll
        for (int j = 0; j < 16; ++j) {
            fx4 v = f[j];
            unsigned e = (unsigned)(v.x == Tf) + (unsigned)(v.y == Tf)
                       + (unsigned)(v.z == Tf) + (unsigned)(v.w == Tf);
            unsigned inc = e;
#pragma unroll
            for (int off = 1; off < 64; off <<= 1) {
                unsigned n = __shfl_up(inc, off, 64);
                if (lane >= off) inc += n;
            }
            unsigned rk  = rank_base + (inc - e);        // exclusive prefix
            unsigned tot = __shfl(inc, 63, 64);          // chunk total

            fx4 w;
            if (v.x == Tf) { w.x = (rk < r) ? v.x : 0.0f; ++rk; }
            else           { w.x = (v.x > Tf) ? v.x : 0.0f; }
            if (v.y == Tf) { w.y = (rk < r) ? v.y : 0.0f; ++rk; }
            else           { w.y = (v.y > Tf) ? v.y : 0.0f; }
            if (v.z == Tf) { w.z = (rk < r) ? v.z : 0.0f; ++rk; }
            else           { w.z = (v.z > Tf) ? v.z : 0.0f; }
            if (v.w == Tf) { w.w = (rk < r) ? v.w : 0.0f; ++rk; }
            else           { w.w = (v.w > Tf) ? v.w : 0.0f; }
            __builtin_nontemporal_store(w, &o[j * 64 + lane]);

            rank_base += tot;
        }
    }
}

extern "C" void kernel_launch(void* const* d_in, const int* in_sizes, int n_in,
                              void* d_out, int out_size, void* d_ws, size_t ws_size,
                              hipStream_t stream) {
    const float* x = (const float*)d_in[0];
    float* out = (float*)d_out;
    const int rows = out_size / ROW;            // 16384
    kwta_kernel<<<rows / RPB, NTHR, 0, stream>>>(x, out);
}